// Round 17
// baseline (547.442 us; speedup 1.0000x reference)
//
#include <hip/hip_runtime.h>
#include <cstdint>

#define NPTOT 17742     // (67^2+33^2+16^2+8^2+4^2)*3
#define FEAT 117        // 4 bbox + 81 conf + 32 mask
#define HCOUT 351       // fused head channels: 12 bbox + 243 conf + 96 mask
#define HROWS 384       // padded head weight rows per tap (zero-filled tail)
#define TOTPX 5914      // per-batch fused pixel count 4489+1089+256+64+16

typedef __bf16 bf16x8 __attribute__((ext_vector_type(8)));
typedef unsigned short u16x8 __attribute__((ext_vector_type(8)));
typedef float f32x4 __attribute__((ext_vector_type(4)));

__device__ __forceinline__ unsigned short f2bf(float f) {   // RNE fp32->bf16
  unsigned int u = __float_as_uint(f);
  u += 0x7fffu + ((u >> 16) & 1u);
  return (unsigned short)(u >> 16);
}
__device__ __forceinline__ float bf2f(unsigned short s) {
  return __uint_as_float(((unsigned int)s) << 16);
}
// async global->LDS, 16B per lane; LDS dest = wave-uniform base + lane*16
__device__ __forceinline__ void gload16(const void* g, void* l) {
  __builtin_amdgcn_global_load_lds(
      (const __attribute__((address_space(1))) unsigned int*)g,
      (__attribute__((address_space(3))) unsigned int*)l, 16, 0, 0);
}

// level table: up to 5 levels in one launch (single-level calls use [0])
struct LvTab {
  int pre[6];                      // block-x prefix per level (pre[5]=sentinel)
  int pxIn[5], pxOut[5];           // pixel-base offsets into in/out buffers
  int Hi[5], Wi[5], Ho[5], Wo[5];
  int oStr[5];                     // per-batch output pixel stride
  int pbase[5];                    // prior base (outMode 1)
  int Cin[5];                      // per-level input channels
  int bOff[5];                     // per-level bias offset
  long long wOff[5];               // per-level weight offset (elements)
};

// fused-P geometry (FPX=1): batch-outer [B][5914][256]
__constant__ const int FLB[6] = {0, 4489, 5578, 5834, 5898, 5914};
__constant__ const int FDIM[5] = {67, 33, 16, 8, 4};
__constant__ const int FPBL[5] = {0, 13467, 16734, 17502, 17694};

// ---------------------------------------------------------------------------
// MFMA implicit-GEMM conv, bf16 NHWC, counted-vmcnt 3-buffer pipeline.
// [proven geometry: 128px x 128ch, 4 waves 2x2, wave tile 64x64, BK=32,
//  48KB LDS -> 3 blocks/CU (=768-block residency). Block counts near k*768
//  matter: 784 blocks = 2 epochs = 51% util (round-16 lesson).]
// FPX=0: LvTab-driven levels (block-uniform). FPX=1: fused per-batch pixel
// space TOTPX (batch-outer), per-thread level decode, shared up/head weights.
// Per K-step: vmcnt(4) -> s_barrier -> stage(k+2) -> ds_read buf[k] + 16 MFMA.
template<int NTAP, int FPX>
__global__ __launch_bounds__(256, 3) void k_conv(
    const unsigned short* __restrict__ in,  // bf16 NHWC
    const unsigned short* __restrict__ w2,  // bf16 [tap][CoutRows][ci]
    const float* __restrict__ bias, void* __restrict__ outp,
    const float* __restrict__ zerobuf, LvTab lv,
    int pad, int Cout, int CoutRows, int relu, int outMode)
{
  __shared__ __align__(16) unsigned short A_s[3][128 * 32];  // 8KB per buf
  __shared__ __align__(16) unsigned short B_s[3][128 * 32];

  const int tid  = threadIdx.x;
  const int lane = tid & 63;
  const int wave = tid >> 6;
  const int wm = wave >> 1, wn = wave & 1;
  const int b   = blockIdx.z;

  int Cin, HW, pm0, n0, pbase = 0;
  int Hi = 0, Wi = 0, Ho = 0, Wo = 0;
  long long pxInB, pxOutB, wOffL = 0;
  const float* biasL;
  if constexpr (FPX) {
    Cin = 256; HW = TOTPX;
    pm0 = blockIdx.x * 128; n0 = blockIdx.y * 128;
    pxInB = (long long)b * TOTPX; pxOutB = (long long)b * TOTPX;
    biasL = bias;
  } else {
    int L = 0, bx = blockIdx.x;
    while (bx >= lv.pre[L + 1]) ++L;
    Hi = lv.Hi[L]; Wi = lv.Wi[L]; Ho = lv.Ho[L]; Wo = lv.Wo[L];
    Cin = lv.Cin[L];
    HW = Ho * Wo;
    pm0 = (bx - lv.pre[L]) * 128;
    n0 = blockIdx.y * 128;
    pxInB  = (long long)lv.pxIn[L] + (long long)b * Hi * Wi;
    pxOutB = (long long)lv.pxOut[L] + (long long)b * lv.oStr[L];
    pbase = lv.pbase[L];
    biasL = bias + lv.bOff[L];
    wOffL = lv.wOff[L];
  }

  // staging geometry: issue q = wave*2+i covers rows q*16..q*16+15;
  // lane l -> row q*16 + (l>>2); source chunk c = (l&3) ^ ((l>>3)&3)  [swizzle]
  const int q0 = wave * 2;
  const int lr = lane >> 2;
  const int cmap = (((lane & 3) ^ ((lane >> 3) & 3)) << 3);  // shorts

  // ---- one-time staging precompute: base addrs + tap validity + widths ----
  const unsigned short* aBase[2];
  const unsigned short* bBase[2];
  unsigned vmask[2];
  int WiCin[2] = {0, 0};
#pragma unroll
  for (int i = 0; i < 2; ++i) {
    const int row = (q0 + i) * 16 + lr;
    const int p = pm0 + row;
    const bool apv = p < HW;
    const int pp = apv ? p : 0;
    unsigned mb = 0;
    if constexpr (FPX) {
      int Lp = 0;
      while (pp >= FLB[Lp + 1]) ++Lp;
      const int W = FDIM[Lp];
      const int lp = pp - FLB[Lp];
      const int ay = lp / W, ax = lp - (lp / W) * W;
      aBase[i] = in + (pxInB + pp) * 256 + cmap;
      WiCin[i] = W * 256;
      if (apv) {
#pragma unroll
        for (int t = 0; t < NTAP; ++t) {
          const int ky = t / 3, kx = t - (t / 3) * 3;
          const int iy = ay + ky - 1, ix = ax + kx - 1;
          if ((unsigned)iy < (unsigned)W && (unsigned)ix < (unsigned)W) mb |= (1u << t);
        }
      }
      bBase[i] = w2 + (size_t)(n0 + row) * 256 + cmap;
    } else {
      const int ay = pp / Wo, ax = pp - (pp / Wo) * Wo;
      aBase[i] = in + (pxInB + (long long)ay * Wi + ax) * Cin + cmap;
      bBase[i] = w2 + wOffL + (size_t)(n0 + row) * Cin + cmap;
      if (apv) {
#pragma unroll
        for (int t = 0; t < NTAP; ++t) {
          const int ky = t / 3, kx = t - (t / 3) * 3;
          const int iy = ay + ky - pad, ix = ax + kx - pad;
          if ((unsigned)iy < (unsigned)Hi && (unsigned)ix < (unsigned)Wi) mb |= (1u << t);
        }
      }
    }
    vmask[i] = mb;
  }
  const unsigned short* zbuf16 = (const unsigned short*)zerobuf;
  const size_t tapW = (size_t)CoutRows * Cin;        // weight tap stride

  f32x4 acc[4][4];
#pragma unroll
  for (int m = 0; m < 4; ++m)
#pragma unroll
    for (int n = 0; n < 4; ++n) acc[m][n] = (f32x4)0.0f;

  // swizzled fragment read offsets (shorts, within one 4096-short buffer)
  const int fl = lane & 15, fq = lane >> 4;
  int offA[4], offB[4];
#pragma unroll
  for (int m = 0; m < 4; ++m) {
    const int rA = wm * 64 + m * 16 + fl;
    offA[m] = rA * 32 + ((fq ^ ((rA >> 1) & 3)) << 3);
    const int rB = wn * 64 + m * 16 + fl;
    offB[m] = rB * 32 + ((fq ^ ((rB >> 1) & 3)) << 3);
  }

  auto stage = [&](int cs, int tap, int buf) {
    const int ky = tap / 3, kx = tap - (tap / 3) * 3;       // folds when const
    const size_t wOff = (size_t)tap * tapW + (cs << 5);
#pragma unroll
    for (int i = 0; i < 2; ++i) {
      const unsigned short* ga;
      if ((vmask[i] >> tap) & 1) {
        int dA;
        if constexpr (FPX) dA = (ky - 1) * WiCin[i] + (kx - 1) * 256;
        else               dA = ((ky - pad) * Wi + (kx - pad)) * Cin;
        ga = aBase[i] + (cs << 5) + dA;
      } else ga = zbuf16;
      gload16(ga, (void*)&A_s[buf][(q0 + i) * 512]);
      gload16(bBase[i] + wOff, (void*)&B_s[buf][(q0 + i) * 512]);
    }
  };

  auto compute = [&](int buf) {
    const unsigned short* Ab = A_s[buf];
    const unsigned short* Bb = B_s[buf];
    bf16x8 afr[4], bfr[4];
#pragma unroll
    for (int m = 0; m < 4; ++m) afr[m] = *(const bf16x8*)&Ab[offA[m]];
#pragma unroll
    for (int n = 0; n < 4; ++n) bfr[n] = *(const bf16x8*)&Bb[offB[n]];
    __builtin_amdgcn_s_setprio(1);
#pragma unroll
    for (int m = 0; m < 4; ++m)
#pragma unroll
      for (int n = 0; n < 4; ++n)
        acc[m][n] = __builtin_amdgcn_mfma_f32_16x16x32_bf16(afr[m], bfr[n], acc[m][n], 0, 0, 0);
    __builtin_amdgcn_s_setprio(0);
  };

  const int ncs = Cin >> 5;
  const int nk = NTAP * ncs;

  if constexpr (NTAP == 9) {
    stage(0, 0, 0);
    stage(0, 1, 1);
    for (int cs = 0; cs < ncs; ++cs) {
#pragma unroll
      for (int tap = 0; tap < 9; ++tap) {
        const int k = cs * 9 + tap;
        if (k + 1 < nk) asm volatile("s_waitcnt vmcnt(4)" ::: "memory");
        else            asm volatile("s_waitcnt vmcnt(0)" ::: "memory");
        __builtin_amdgcn_s_barrier();
        if (k + 2 < nk) {
          const int t2 = (tap + 2 >= 9) ? tap - 7 : tap + 2;   // compile-time
          const int cs2 = cs + ((tap + 2) >= 9 ? 1 : 0);
          stage(cs2, t2, (tap + 2) % 3);
        }
        compute(tap % 3);            // buffer k%3 == tap%3 (9 ≡ 0 mod 3)
      }
    }
  } else {
    stage(0, 0, 0);
    stage(1, 0, 1);
    int cur = 0;
    for (int k = 0; k < nk; ++k) {
      if (k + 1 < nk) asm volatile("s_waitcnt vmcnt(4)" ::: "memory");
      else            asm volatile("s_waitcnt vmcnt(0)" ::: "memory");
      __builtin_amdgcn_s_barrier();
      if (k + 2 < nk) {
        int tgt = cur + 2; if (tgt >= 3) tgt -= 3;
        stage(k + 2, 0, tgt);
      }
      compute(cur);
      cur = (cur == 2) ? 0 : cur + 1;
    }
  }

  // epilogue: D row = pixel = (lane>>4)*4 + r, col = channel = lane&15
  const int chl = lane & 15;
  const int pxq = (lane >> 4) * 4;
  if (outMode == 0) {
    unsigned short* outb = (unsigned short*)outp;
#pragma unroll
    for (int n = 0; n < 4; ++n) {
      const int ch = n0 + wn * 64 + n * 16 + chl;
      const float bb = biasL[ch];
#pragma unroll
      for (int m = 0; m < 4; ++m) {
        const int pxb = pm0 + wm * 64 + m * 16 + pxq;
#pragma unroll
        for (int r = 0; r < 4; ++r) {
          const int p = pxb + r;
          if (p < HW) {
            float vv = acc[m][n][r] + bb;
            if (relu) vv = fmaxf(vv, 0.f);
            outb[(pxOutB + p) * 256 + ch] = f2bf(vv);
          }
        }
      }
    }
  } else {
    float* outf = (float*)outp;
#pragma unroll
    for (int n = 0; n < 4; ++n) {
      const int co = n0 + wn * 64 + n * 16 + chl;
      if (co < HCOUT) {
        int aIdx, k2, off, isT = 0;
        if (co < 12)       { aIdx = co >> 2; k2 = co & 3; off = 0; }
        else if (co < 255) { int c = co - 12; aIdx = (c >= 162) ? 2 : (c >= 81 ? 1 : 0);
                             k2 = c - aIdx * 81; off = 4; }
        else               { int c = co - 255; aIdx = c >> 5; k2 = c & 31; off = 85; isT = 1; }
        const float bb = biasL[co];
#pragma unroll
        for (int m = 0; m < 4; ++m) {
          const int pxb = pm0 + wm * 64 + m * 16 + pxq;
#pragma unroll
          for (int r = 0; r < 4; ++r) {
            const int p = pxb + r;
            if (p < HW) {
              float vv = acc[m][n][r] + bb;
              if (isT) vv = tanhf(vv);
              if constexpr (FPX) {
                int Lp = 0;
                while (p >= FLB[Lp + 1]) ++Lp;
                const size_t pri = (size_t)FPBL[Lp] + (size_t)(p - FLB[Lp]) * 3 + aIdx;
                outf[((size_t)b * NPTOT + pri) * FEAT + off + k2] = vv;
              } else {
                outf[((size_t)b * NPTOT + pbase + (size_t)p * 3 + aIdx) * FEAT + off + k2] = vv;
              }
            }
          }
        }
      }
    }
  }
}

// ---------------------------------------------------------------------------
// ONE prep kernel: 10 weight repacks + zerobuf + 3 bias packs + priors.
struct WPrepArgs {
  const float* wsrc[10];
  unsigned long long wdstOff[10];   // element offsets into B0
  int CinA[10], ntapA[10], rsA[10], roA[10];
  long long pre[11];                // weight flat-index prefixes
  const float *bbox_b, *conf_b, *mask_b;
  const float *pb0, *pb1, *pb2;
  const float *lb5, *lb4, *lb3;
};
__global__ __launch_bounds__(256) void k_wprep(
    WPrepArgs a, unsigned short* __restrict__ B0, float* __restrict__ zb,
    float* __restrict__ bias_h, float* __restrict__ biasP,
    float* __restrict__ biasLat, float* __restrict__ priors) {
  long long t = (long long)blockIdx.x * 256 + threadIdx.x;
  if (t < a.pre[10]) {
    int r = 0;
    while (t >= a.pre[r + 1]) ++r;
    long long i = t - a.pre[r];
    const int Cin = a.CinA[r], nt = a.ntapA[r];
    const int cn = Cin * nt;
    const int co = (int)(i / cn);
    const int rem = (int)(i - (long long)co * cn);
    const int ci = rem / nt, tap = rem - (rem / nt) * nt;
    B0[a.wdstOff[r] + ((size_t)tap * a.rsA[r] + a.roA[r] + co) * Cin + ci] = f2bf(a.wsrc[r][i]);
    return;
  }
  t -= a.pre[10];
  if (t < 256) { zb[t] = 0.f; return; }
  t -= 256;
  if (t < 384) {
    int co = (int)t; float v = 0.f;
    if (co < 12) v = a.bbox_b[co];
    else if (co < 255) v = a.conf_b[co - 12];
    else if (co < HCOUT) v = a.mask_b[co - 255];
    bias_h[co] = v; return;
  }
  t -= 384;
  if (t < 768) {
    float v = (t < 256) ? a.pb2[t] : (t < 512 ? a.pb1[t - 256] : a.pb0[t - 512]);
    biasP[t] = v; return;
  }
  t -= 768;
  if (t < 768) {
    float v = (t < 256) ? a.lb5[t] : (t < 512 ? a.lb4[t - 256] : a.lb3[t - 512]);
    biasLat[t] = v; return;
  }
  t -= 768;
  if (t < NPTOT) {
    int pi = (int)t;
    const int sizes[5] = {67, 33, 16, 8, 4};
    int idx = pi, H = 4;
#pragma unroll
    for (int L = 0; L < 5; ++L) {
      int cnt = sizes[L] * sizes[L] * 3;
      if (idx < cnt) { H = sizes[L]; break; }
      idx -= cnt;
    }
    int ar = idx % 3; int cell = idx / 3;
    int x = cell % H; int y = cell / H;
    const float ars[3] = {1.0f, 0.5f, 2.0f};
    priors[pi * 4 + 0] = (x + 0.5f) / (float)H;
    priors[pi * 4 + 1] = (y + 0.5f) / (float)H;
    priors[pi * 4 + 2] = 3.0f * ars[ar] / (float)H;
    priors[pi * 4 + 3] = 3.0f / ars[ar] / (float)H;
  }
}

// ---------------------------------------------------------------------------
// table-driven fp32 NCHW -> bf16 NHWC transpose (up to 3 levels per launch)
struct TTab {
  int pre[4];                       // block prefix; pre[nL] = total
  int nx[3];                        // pixel-tile count per level
  int C[3], HW[3];
  unsigned long long dOff[3];       // dest element offsets in R
};
__global__ __launch_bounds__(256) void k_tonhwcN(
    TTab t, const float* __restrict__ s0, const float* __restrict__ s1,
    const float* __restrict__ s2, unsigned short* __restrict__ R) {
  __shared__ float sm[64][65];
  int L = 0, bx = blockIdx.x;
  while (bx >= t.pre[L + 1]) ++L;
  const int tI = bx - t.pre[L];
  const int p0 = (tI % t.nx[L]) * 64, c0 = (tI / t.nx[L]) * 64;
  const int C = t.C[L], HW = t.HW[L], b = blockIdx.z;
  const float* src = (L == 0) ? s0 : (L == 1 ? s1 : s2);
  const int tid = threadIdx.x;
  const float* ib = src + ((size_t)b * C + c0) * HW;
#pragma unroll 4
  for (int r = 0; r < 16; ++r) {
    int ch = r * 4 + (tid >> 6);
    int px = tid & 63;
    sm[ch][px] = (p0 + px < HW) ? ib[(size_t)ch * HW + p0 + px] : 0.f;
  }
  __syncthreads();
#pragma unroll 4
  for (int r = 0; r < 16; ++r) {
    int px = r * 4 + (tid >> 6);
    int ch = tid & 63;
    if (p0 + px < HW)
      R[t.dOff[L] + ((size_t)b * HW + p0 + px) * C + c0 + ch] = f2bf(sm[ch][px]);
  }
}

// ---------------------------------------------------------------------------
// jax-exact bilinear resize add, bf16 NHWC, C=256. thread = 8ch of one out px.
__global__ __launch_bounds__(256) void k_resize_add_nhwc(
    const unsigned short* __restrict__ in, unsigned short* __restrict__ out,
    int Hi, int Wi, int Ho, int Wo) {
  int idx = blockIdx.x * 256 + threadIdx.x;
  int HW = Ho * Wo;
  if (idx >= HW * 32) return;
  int b = blockIdx.z;
  int c0 = (idx & 31) * 8;
  int p = idx >> 5;
  int y = p / Wo, x = p - y * Wo;
  float sy = (y + 0.5f) * (float)Hi / (float)Ho - 0.5f;
  float sx = (x + 0.5f) * (float)Wi / (float)Wo - 0.5f;
  int iy0 = (int)floorf(sy), ix0 = (int)floorf(sx);
  float wy1 = sy - (float)iy0, wy0 = 1.f - wy1;
  float wx1 = sx - (float)ix0, wx0 = 1.f - wx1;
  if (iy0 < 0 || iy0 >= Hi) wy0 = 0.f;
  if (iy0 + 1 < 0 || iy0 + 1 >= Hi) wy1 = 0.f;
  if (ix0 < 0 || ix0 >= Wi) wx0 = 0.f;
  if (ix0 + 1 < 0 || ix0 + 1 >= Wi) wx1 = 0.f;
  float ty_ = wy0 + wy1, tx_ = wx0 + wx1;
  wy0 /= ty_; wy1 /= ty_; wx0 /= tx_; wx1 /= tx_;
  int y0 = min(max(iy0, 0), Hi - 1), y1 = min(max(iy0 + 1, 0), Hi - 1);
  int x0 = min(max(ix0, 0), Wi - 1), x1 = min(max(ix0 + 1, 0), Wi - 1);
  const unsigned short* ib = in + (size_t)b * Hi * Wi * 256;
  u16x8 v00 = *(const u16x8*)&ib[((size_t)y0 * Wi + x0) * 256 + c0];
  u16x8 v01 = *(const u16x8*)&ib[((size_t)y0 * Wi + x1) * 256 + c0];
  u16x8 v10 = *(const u16x8*)&ib[((size_t)y1 * Wi + x0) * 256 + c0];
  u16x8 v11 = *(const u16x8*)&ib[((size_t)y1 * Wi + x1) * 256 + c0];
  unsigned short* ob = out + ((size_t)b * HW + p) * 256 + c0;
  u16x8 cur = *(u16x8*)ob, res;
#pragma unroll
  for (int i = 0; i < 8; ++i) {
    float bl = wy0 * (wx0 * bf2f(v00[i]) + wx1 * bf2f(v01[i])) +
               wy1 * (wx0 * bf2f(v10[i]) + wx1 * bf2f(v11[i]));
    res[i] = f2bf(bf2f(cur[i]) + bl);
  }
  *(u16x8*)ob = res;
}

// ---------------------------------------------------------------------------
// strided downsample within the batch-outer fused P space
__global__ __launch_bounds__(256) void k_down_f(
    unsigned short* __restrict__ P, int inBase, int outBase, int Wi) {
  int Wo = Wi / 2;
  int total = Wo * Wo * 32;
  int idx = blockIdx.x * 256 + threadIdx.x;
  if (idx >= total) return;
  int b = blockIdx.z;
  int c0 = (idx & 31) * 8;
  int p = idx >> 5;
  int y = p / Wo, x = p - y * Wo;
  *(u16x8*)&P[((size_t)b * TOTPX + outBase + p) * 256 + c0] =
      *(const u16x8*)&P[((size_t)b * TOTPX + inBase + (2 * y) * Wi + 2 * x) * 256 + c0];
}

// ---------------------------------------------------------------------------
__global__ __launch_bounds__(256) void priors_kernel(float* __restrict__ pr) {
  int pi = blockIdx.x * 256 + threadIdx.x;
  if (pi >= NPTOT) return;
  const int sizes[5] = {67, 33, 16, 8, 4};
  int idx = pi, H = 4;
#pragma unroll
  for (int L = 0; L < 5; ++L) {
    int cnt = sizes[L] * sizes[L] * 3;
    if (idx < cnt) { H = sizes[L]; break; }
    idx -= cnt;
  }
  int a = idx % 3; int cell = idx / 3;
  int x = cell % H; int y = cell / H;
  const float ars[3] = {1.0f, 0.5f, 2.0f};
  pr[pi * 4 + 0] = (x + 0.5f) / (float)H;
  pr[pi * 4 + 1] = (y + 0.5f) / (float)H;
  pr[pi * 4 + 2] = 3.0f * ars[a] / (float)H;
  pr[pi * 4 + 3] = 3.0f / ars[a] / (float)H;
}

// ---------------------------------------------------------------------------
extern "C" void kernel_launch(void* const* d_in, const int* in_sizes, int n_in,
                              void* d_out, int out_size, void* d_ws, size_t ws_size,
                              hipStream_t stream) {
  const float* c3 = (const float*)d_in[0];
  const float* c4 = (const float*)d_in[1];
  const float* c5 = (const float*)d_in[2];
  const float* lat_w5 = (const float*)d_in[3];  const float* lat_b5 = (const float*)d_in[4];
  const float* lat_w4 = (const float*)d_in[5];  const float* lat_b4 = (const float*)d_in[6];
  const float* lat_w3 = (const float*)d_in[7];  const float* lat_b3 = (const float*)d_in[8];
  const float* pred_w0 = (const float*)d_in[9];  const float* pred_b0 = (const float*)d_in[10];
  const float* pred_w1 = (const float*)d_in[11]; const float* pred_b1 = (const float*)d_in[12];
  const float* pred_w2 = (const float*)d_in[13]; const float* pred_b2 = (const float*)d_in[14];
  const float* up_w = (const float*)d_in[15];  const float* up_b = (const float*)d_in[16];
  const float* bbox_w = (const float*)d_in[17]; const float* bbox_b = (const float*)d_in[18];
  const float* conf_w = (const float*)d_in[19]; const float* conf_b = (const float*)d_in[20];
  const float* mask_w = (const float*)d_in[21]; const float* mask_b = (const float*)d_in[22];

  float* out = (float*)d_out;
  float* priors = out + (size_t)8 * NPTOT * FEAT;

  // workspace layout (bf16 element offsets); peak 48,701,696 elem = 97.40 MB
  unsigned short* B0 = (unsigned short*)d_ws;
  unsigned short* w2_pred0 = B0 + 524288;    // (lat5 at 0)
  unsigned short* w2_up    = B0 + 2686976;
  unsigned short* w2_head  = B0 + 3276800;   // 9*384*256 = 884736 -> 4161536
  unsigned short* x5 = B0 + 4161536;         // 663552   -> 4825088
  unsigned short* x4 = B0 + 4825088;         // 2508800  -> 7333888
  unsigned short* x3 = B0 + 7333888;         // 9750528  -> 17084416
  unsigned short* P  = B0 + 17084416;        // 8*5914*256 = 12111872 -> 29196288
  unsigned short* R  = B0 + 29196288;        // 19501056 -> 48697344
  float* bias_h  = (float*)(B0 + 48697344);  // 384 f32  -> 48698112
  float* zb      = (float*)(B0 + 48698112);  // 256 f32  -> 48698624
  float* biasP   = (float*)(B0 + 48698624);  // 768 f32  -> 48700160
  float* biasLat = (float*)(B0 + 48700160);  // 768 f32  -> 48701696
  unsigned short* U = R;                     // R dead after FPN; 12.1M <= 19.5M

  if (ws_size < 48701696ull * 2ull) {        // diagnostic: priors only
    priors_kernel<<<dim3((NPTOT + 255) / 256), dim3(256), 0, stream>>>(priors);
    return;
  }

  // ---- ONE fused prep launch (after zero-padding head weights) ----
  hipMemsetAsync(w2_head, 0, 9ull * HROWS * 256 * 2, stream);
  {
    WPrepArgs a{};
    const float* srcs[10] = {lat_w5, pred_w0, lat_w4, pred_w1, lat_w3, pred_w2,
                             up_w, bbox_w, conf_w, mask_w};
    const unsigned long long dsts[10] = {0, 524288, 1114112, 1376256, 1966080,
                                         2097152, 2686976, 3276800, 3276800, 3276800};
    const int cins[10] = {2048, 256, 1024, 256, 512, 256, 256, 256, 256, 256};
    const int ntaps[10] = {1, 9, 1, 9, 1, 9, 9, 9, 9, 9};
    const int couts[10] = {256, 256, 256, 256, 256, 256, 256, 12, 243, 96};
    const int rss[10] = {256, 256, 256, 256, 256, 256, 256, HROWS, HROWS, HROWS};
    const int ros[10] = {0, 0, 0, 0, 0, 0, 0, 0, 12, 255};
    long long cum = 0;
    for (int i = 0; i < 10; ++i) {
      a.wsrc[i] = srcs[i]; a.wdstOff[i] = dsts[i];
      a.CinA[i] = cins[i]; a.ntapA[i] = ntaps[i]; a.rsA[i] = rss[i]; a.roA[i] = ros[i];
      a.pre[i] = cum;
      cum += (long long)cins[i] * ntaps[i] * couts[i];
    }
    a.pre[10] = cum;                           // = 4,085,504
    a.bbox_b = bbox_b; a.conf_b = conf_b; a.mask_b = mask_b;
    a.pb0 = pred_b0; a.pb1 = pred_b1; a.pb2 = pred_b2;
    a.lb5 = lat_b5; a.lb4 = lat_b4; a.lb3 = lat_b3;
    long long total = cum + 256 + 384 + 768 + 768 + NPTOT;
    k_wprep<<<dim3((unsigned)((total + 255) / 256)), dim3(256), 0, stream>>>(
        a, B0, zb, bias_h, biasP, biasLat, priors);
  }

  // ---- group A: transpose c5+c4 concat into R (15.3M <= 19.5M elems) ----
  {
    TTab t{};
    t.pre[0] = 0; t.pre[1] = 192; t.pre[2] = 512; t.pre[3] = 512;
    t.nx[0] = 6;  t.nx[1] = 20;
    t.C[0] = 2048; t.C[1] = 1024;
    t.HW[0] = 324; t.HW[1] = 1225;
    t.dOff[0] = 0ull; t.dOff[1] = 5308416ull;       // 8*324*2048
    k_tonhwcN<<<dim3(512, 1, 8), dim3(256), 0, stream>>>(t, c5, c4, c3, R);
  }
  // ---- batched lateral conv {lat5->x5, lat4->x4} ----
  {
    LvTab lv{};
    const int Hs[2] = {18, 35};
    const int cins[2] = {2048, 1024};
    const int pxIn[2] = {0, 5184};             // 5,308,416 / 1024
    const int pxOut[2] = {0, 2592};            // x4 rel x5 (px, stride 256)
    const long long wOff[2] = {0, 1114112};
    int acc_ = 0;
    for (int i = 0; i < 2; ++i) {
      lv.pre[i] = acc_;
      acc_ += (Hs[i] * Hs[i] + 127) / 128;
      lv.Hi[i] = Hs[i]; lv.Wi[i] = Hs[i]; lv.Ho[i] = Hs[i]; lv.Wo[i] = Hs[i];
      lv.Cin[i] = cins[i]; lv.pxIn[i] = pxIn[i]; lv.pxOut[i] = pxOut[i];
      lv.oStr[i] = Hs[i] * Hs[i];
      lv.pbase[i] = 0; lv.bOff[i] = i * 256; lv.wOff[i] = wOff[i];
    }
    lv.pre[2] = acc_; lv.pre[3] = lv.pre[4] = lv.pre[5] = 2000000000;
    dim3 g(acc_, 2, 8);
    k_conv<1, 0><<<g, dim3(256), 0, stream>>>(R, B0, biasLat, x5, zb, lv,
                                              0, 256, 256, 0, 0);
  }
  // ---- group B: transpose c3 into R (19.5M = R exactly) + lat3->x3 ----
  {
    TTab t{};
    t.pre[0] = 0; t.pre[1] = 600; t.pre[2] = 600; t.pre[3] = 600;
    t.nx[0] = 75; t.C[0] = 512; t.HW[0] = 4761; t.dOff[0] = 0ull;
    k_tonhwcN<<<dim3(600, 1, 8), dim3(256), 0, stream>>>(t, c3, c4, c5, R);
  }
  {
    LvTab lv{};
    lv.pre[0] = 0; lv.pre[1] = 38;             // ceil(4761/128)
    lv.pre[2] = lv.pre[3] = lv.pre[4] = lv.pre[5] = 2000000000;
    lv.Hi[0] = 69; lv.Wi[0] = 69; lv.Ho[0] = 69; lv.Wo[0] = 69;
    lv.Cin[0] = 512; lv.pxIn[0] = 0; lv.pxOut[0] = 12392;   // x3 rel x5
    lv.oStr[0] = 69 * 69;
    lv.pbase[0] = 0; lv.bOff[0] = 512; lv.wOff[0] = 1966080;
    dim3 g(38, 2, 8);
    k_conv<1, 0><<<g, dim3(256), 0, stream>>>(R, B0, biasLat, x5, zb, lv,
                                              0, 256, 256, 0, 0);
  }

  // ---- resize chain (serial dependency) ----
  k_resize_add_nhwc<<<dim3((1225 * 32 + 255) / 256, 1, 8), dim3(256), 0, stream>>>(x5, x4, 18, 18, 35, 35);
  k_resize_add_nhwc<<<dim3((4761 * 32 + 255) / 256, 1, 8), dim3(256), 0, stream>>>(x4, x3, 35, 35, 69, 69);

  // ---- pred convs: ONE batched launch -> fused P (batch-outer) ----
  {
    LvTab lv{};
    const int HiL[3] = {69, 35, 18}, HoL[3] = {67, 33, 16};
    const long long wOffL[3] = {1572864, 851968, 0};   // pred2/1/0 rel w2_pred0
    const int pxInL[3]  = {12392, 2592, 0};            // x3/x4/x5 rel x5 (px)
    const int pxOutL[3] = {0, 4489, 5578};             // p3/p4/p5 within batch
    const int bOffL[3]  = {0, 256, 512};               // biasP packing
    int acc_ = 0;
    for (int i = 0; i < 3; ++i) {
      lv.pre[i] = acc_;
      acc_ += (HoL[i] * HoL[i] + 127) / 128;
      lv.pxIn[i] = pxInL[i]; lv.pxOut[i] = pxOutL[i];
      lv.Hi[i] = HiL[i]; lv.Wi[i] = HiL[i]; lv.Ho[i] = HoL[i]; lv.Wo[i] = HoL[i];
      lv.oStr[i] = TOTPX;                              // batch-outer P
      lv.pbase[i] = 0; lv.Cin[i] = 256; lv.bOff[i] = bOffL[i]; lv.wOff[i] = wOffL[i];
    }
    lv.pre[3] = acc_; lv.pre[4] = lv.pre[5] = 2000000000;
    dim3 g(acc_, 2, 8);
    k_conv<9, 0><<<g, dim3(256), 0, stream>>>(x5, w2_pred0, biasP, P, zb, lv,
                                              0, 256, 256, 1, 0);
  }
  k_down_f<<<dim3(8, 1, 8), dim3(256), 0, stream>>>(P, 5578, 5834, 16);   // p5->p6
  k_down_f<<<dim3(2, 1, 8), dim3(256), 0, stream>>>(P, 5834, 5898, 8);    // p6->p7

  // ---- heads: fused-pixel-space up-conv (752 blocks = 1 epoch) + head ----
  {
    LvTab lv{};   // unused in FPX path
    dim3 gu(47, 2, 8);                                // ceil(5914/128)=47
    k_conv<9, 1><<<gu, dim3(256), 0, stream>>>(P, w2_up, up_b, U, zb, lv,
                                               1, 256, 256, 1, 0);
    dim3 gh(47, 3, 8);
    k_conv<9, 1><<<gh, dim3(256), 0, stream>>>(U, w2_head, bias_h, out, zb, lv,
                                               1, HCOUT, HROWS, 0, 1);
  }
}

// Round 18
// 530.753 us; speedup vs baseline: 1.0314x; 1.0314x over previous
//
#include <hip/hip_runtime.h>
#include <cstdint>

#define NPTOT 17742     // (67^2+33^2+16^2+8^2+4^2)*3
#define FEAT 117        // 4 bbox + 81 conf + 32 mask
#define HCOUT 351       // fused head channels: 12 bbox + 243 conf + 96 mask
#define HROWS 384       // padded head weight rows per tap (zero-filled tail)

typedef __bf16 bf16x8 __attribute__((ext_vector_type(8)));
typedef unsigned short u16x8 __attribute__((ext_vector_type(8)));
typedef float f32x4 __attribute__((ext_vector_type(4)));

__device__ __forceinline__ unsigned short f2bf(float f) {   // RNE fp32->bf16
  unsigned int u = __float_as_uint(f);
  u += 0x7fffu + ((u >> 16) & 1u);
  return (unsigned short)(u >> 16);
}
__device__ __forceinline__ float bf2f(unsigned short s) {
  return __uint_as_float(((unsigned int)s) << 16);
}
// async global->LDS, 16B per lane; LDS dest = wave-uniform base + lane*16
__device__ __forceinline__ void gload16(const void* g, void* l) {
  __builtin_amdgcn_global_load_lds(
      (const __attribute__((address_space(1))) unsigned int*)g,
      (__attribute__((address_space(3))) unsigned int*)l, 16, 0, 0);
}

// level table: up to 5 levels in one launch (single-level calls use [0])
struct LvTab {
  int pre[6];                      // block-x prefix per level (pre[5]=sentinel)
  int pxIn[5], pxOut[5];           // pixel-base offsets into in/out buffers
  int Hi[5], Wi[5], Ho[5], Wo[5];
  int pbase[5];                    // prior base (outMode 1)
  int Cin[5];                      // per-level input channels
  int bOff[5];                     // per-level bias offset
  long long wOff[5];               // per-level weight offset (elements)
};

// ---------------------------------------------------------------------------
// MFMA implicit-GEMM conv, bf16 NHWC, counted-vmcnt 3-buffer pipeline.
// [proven geometry: 128px x 128ch, 4 waves 2x2, wave tile 64x64, BK=32,
//  48KB LDS -> 3 blocks/CU. 256px tile (72KB, 2 blocks/CU) REGRESSED (r14);
//  fused-pixel-space decode REGRESSED (r17). This is the r16 best-known.]
// K-order: ci-slab OUTER, tap INNER (compile-time-unrolled for NTAP==9).
// Per K-step: vmcnt(4) -> s_barrier -> stage(k+2) -> ds_read buf[k] + 16 MFMA.
// LDS chunk-swizzle via pre-swizzled per-lane GLOBAL source (rule #21).
template<int NTAP>
__global__ __launch_bounds__(256, 3) void k_conv(
    const unsigned short* __restrict__ in,  // bf16 NHWC [.][px][Cin]
    const unsigned short* __restrict__ w2,  // bf16 [tap][CoutRows][ci]
    const float* __restrict__ bias, void* __restrict__ outp,
    const float* __restrict__ zerobuf, LvTab lv,
    int pad, int Cout, int CoutRows, int relu, int outMode)
{
  __shared__ __align__(16) unsigned short A_s[3][128 * 32];  // 8KB per buf
  __shared__ __align__(16) unsigned short B_s[3][128 * 32];

  const int tid  = threadIdx.x;
  const int lane = tid & 63;
  const int wave = tid >> 6;
  const int wm = wave >> 1, wn = wave & 1;
  const int b   = blockIdx.z;

  // level decode (wave-uniform)
  int L = 0, bx = blockIdx.x;
  while (bx >= lv.pre[L + 1]) ++L;
  const int Hi = lv.Hi[L], Wi = lv.Wi[L], Ho = lv.Ho[L], Wo = lv.Wo[L];
  const int Cin = lv.Cin[L];
  const int HW = Ho * Wo;
  const int pm0 = (bx - lv.pre[L]) * 128;
  const int n0  = blockIdx.y * 128;
  const long long pxInB  = (long long)lv.pxIn[L]  + (long long)b * Hi * Wi;
  const long long pxOutB = (long long)lv.pxOut[L] + (long long)b * HW;
  const int pbase = lv.pbase[L];
  const float* biasL = bias + lv.bOff[L];

  // staging geometry: issue q = wave*2+i covers rows q*16..q*16+15;
  // lane l -> row q*16 + (l>>2); source chunk c = (l&3) ^ ((l>>3)&3)  [swizzle]
  const int q0 = wave * 2;
  const int lr = lane >> 2;
  const int cmap = (((lane & 3) ^ ((lane >> 3) & 3)) << 3);  // shorts

  // ---- one-time staging precompute: base addrs + 9-bit tap validity ----
  const unsigned short* aBase[2];
  const unsigned short* bBase[2];
  unsigned vmask[2];
#pragma unroll
  for (int i = 0; i < 2; ++i) {
    const int row = (q0 + i) * 16 + lr;
    const int p = pm0 + row;
    const bool apv = p < HW;
    const int pp = apv ? p : 0;
    const int ay = pp / Wo, ax = pp - (pp / Wo) * Wo;
    aBase[i] = in + (pxInB + (long long)ay * Wi + ax) * Cin + cmap;
    bBase[i] = w2 + lv.wOff[L] + (size_t)(n0 + row) * Cin + cmap;
    unsigned mb = 0;
    if (apv) {
#pragma unroll
      for (int t = 0; t < NTAP; ++t) {
        const int ky = t / 3, kx = t - (t / 3) * 3;
        const int iy = ay + ky - pad, ix = ax + kx - pad;
        if ((unsigned)iy < (unsigned)Hi && (unsigned)ix < (unsigned)Wi) mb |= (1u << t);
      }
    }
    vmask[i] = mb;
  }
  const unsigned short* zbuf16 = (const unsigned short*)zerobuf;
  const size_t tapW = (size_t)CoutRows * Cin;        // weight tap stride

  f32x4 acc[4][4];
#pragma unroll
  for (int m = 0; m < 4; ++m)
#pragma unroll
    for (int n = 0; n < 4; ++n) acc[m][n] = (f32x4)0.0f;

  // swizzled fragment read offsets (shorts, within one 4096-short buffer)
  const int fl = lane & 15, fq = lane >> 4;
  int offA[4], offB[4];
#pragma unroll
  for (int m = 0; m < 4; ++m) {
    const int rA = wm * 64 + m * 16 + fl;
    offA[m] = rA * 32 + ((fq ^ ((rA >> 1) & 3)) << 3);
    const int rB = wn * 64 + m * 16 + fl;
    offB[m] = rB * 32 + ((fq ^ ((rB >> 1) & 3)) << 3);
  }

  auto stage = [&](int cs, int tap, int buf) {
    const int ky = tap / 3, kx = tap - (tap / 3) * 3;       // folds when const
    const int dA = ((ky - pad) * Wi + (kx - pad)) * Cin;    // uniform
    const size_t wOff = (size_t)tap * tapW + (cs << 5);
    const int aOff = (cs << 5) + dA;
#pragma unroll
    for (int i = 0; i < 2; ++i) {
      const unsigned short* ga = ((vmask[i] >> tap) & 1) ? (aBase[i] + aOff) : zbuf16;
      gload16(ga, (void*)&A_s[buf][(q0 + i) * 512]);
      gload16(bBase[i] + wOff, (void*)&B_s[buf][(q0 + i) * 512]);
    }
  };

  auto compute = [&](int buf) {
    const unsigned short* Ab = A_s[buf];
    const unsigned short* Bb = B_s[buf];
    bf16x8 afr[4], bfr[4];
#pragma unroll
    for (int m = 0; m < 4; ++m) afr[m] = *(const bf16x8*)&Ab[offA[m]];
#pragma unroll
    for (int n = 0; n < 4; ++n) bfr[n] = *(const bf16x8*)&Bb[offB[n]];
    __builtin_amdgcn_s_setprio(1);
#pragma unroll
    for (int m = 0; m < 4; ++m)
#pragma unroll
      for (int n = 0; n < 4; ++n)
        acc[m][n] = __builtin_amdgcn_mfma_f32_16x16x32_bf16(afr[m], bfr[n], acc[m][n], 0, 0, 0);
    __builtin_amdgcn_s_setprio(0);
  };

  const int ncs = Cin >> 5;
  const int nk = NTAP * ncs;

  if constexpr (NTAP == 9) {
    stage(0, 0, 0);
    stage(0, 1, 1);
    for (int cs = 0; cs < ncs; ++cs) {
#pragma unroll
      for (int tap = 0; tap < 9; ++tap) {
        const int k = cs * 9 + tap;
        if (k + 1 < nk) asm volatile("s_waitcnt vmcnt(4)" ::: "memory");
        else            asm volatile("s_waitcnt vmcnt(0)" ::: "memory");
        __builtin_amdgcn_s_barrier();
        if (k + 2 < nk) {
          const int t2 = (tap + 2 >= 9) ? tap - 7 : tap + 2;   // compile-time
          const int cs2 = cs + ((tap + 2) >= 9 ? 1 : 0);
          stage(cs2, t2, (tap + 2) % 3);
        }
        compute(tap % 3);            // buffer k%3 == tap%3 (9 ≡ 0 mod 3)
      }
    }
  } else {
    stage(0, 0, 0);
    stage(1, 0, 1);
    int cur = 0;
    for (int k = 0; k < nk; ++k) {
      if (k + 1 < nk) asm volatile("s_waitcnt vmcnt(4)" ::: "memory");
      else            asm volatile("s_waitcnt vmcnt(0)" ::: "memory");
      __builtin_amdgcn_s_barrier();
      if (k + 2 < nk) {
        int tgt = cur + 2; if (tgt >= 3) tgt -= 3;
        stage(k + 2, 0, tgt);
      }
      compute(cur);
      cur = (cur == 2) ? 0 : cur + 1;
    }
  }

  // epilogue: D row = pixel = (lane>>4)*4 + r, col = channel = lane&15
  const int chl = lane & 15;
  const int pxq = (lane >> 4) * 4;
  if (outMode == 0) {
    unsigned short* outb = (unsigned short*)outp;
#pragma unroll
    for (int n = 0; n < 4; ++n) {
      const int ch = n0 + wn * 64 + n * 16 + chl;
      const float bb = biasL[ch];
#pragma unroll
      for (int m = 0; m < 4; ++m) {
        const int pxb = pm0 + wm * 64 + m * 16 + pxq;
#pragma unroll
        for (int r = 0; r < 4; ++r) {
          const int p = pxb + r;
          if (p < HW) {
            float vv = acc[m][n][r] + bb;
            if (relu) vv = fmaxf(vv, 0.f);
            outb[(pxOutB + p) * 256 + ch] = f2bf(vv);
          }
        }
      }
    }
  } else {
    float* outf = (float*)outp;
#pragma unroll
    for (int n = 0; n < 4; ++n) {
      const int co = n0 + wn * 64 + n * 16 + chl;
      if (co < HCOUT) {
        int aIdx, k2, off, isT = 0;
        if (co < 12)       { aIdx = co >> 2; k2 = co & 3; off = 0; }
        else if (co < 255) { int c = co - 12; aIdx = (c >= 162) ? 2 : (c >= 81 ? 1 : 0);
                             k2 = c - aIdx * 81; off = 4; }
        else               { int c = co - 255; aIdx = c >> 5; k2 = c & 31; off = 85; isT = 1; }
        const float bb = biasL[co];
#pragma unroll
        for (int m = 0; m < 4; ++m) {
          const int pxb = pm0 + wm * 64 + m * 16 + pxq;
#pragma unroll
          for (int r = 0; r < 4; ++r) {
            const int p = pxb + r;
            if (p < HW) {
              float vv = acc[m][n][r] + bb;
              if (isT) vv = tanhf(vv);
              outf[((size_t)b * NPTOT + pbase + (size_t)p * 3 + aIdx) * FEAT + off + k2] = vv;
            }
          }
        }
      }
    }
  }
}

// ---------------------------------------------------------------------------
// ONE prep kernel: 10 weight repacks + zerobuf + 3 bias packs + priors.
struct WPrepArgs {
  const float* wsrc[10];
  unsigned long long wdstOff[10];   // element offsets into B0
  int CinA[10], ntapA[10], rsA[10], roA[10];
  long long pre[11];                // weight flat-index prefixes
  const float *bbox_b, *conf_b, *mask_b;
  const float *pb0, *pb1, *pb2;
  const float *lb5, *lb4, *lb3;
};
__global__ __launch_bounds__(256) void k_wprep(
    WPrepArgs a, unsigned short* __restrict__ B0, float* __restrict__ zb,
    float* __restrict__ bias_h, float* __restrict__ biasP,
    float* __restrict__ biasLat, float* __restrict__ priors) {
  long long t = (long long)blockIdx.x * 256 + threadIdx.x;
  if (t < a.pre[10]) {
    int r = 0;
    while (t >= a.pre[r + 1]) ++r;
    long long i = t - a.pre[r];
    const int Cin = a.CinA[r], nt = a.ntapA[r];
    const int cn = Cin * nt;
    const int co = (int)(i / cn);
    const int rem = (int)(i - (long long)co * cn);
    const int ci = rem / nt, tap = rem - (rem / nt) * nt;
    B0[a.wdstOff[r] + ((size_t)tap * a.rsA[r] + a.roA[r] + co) * Cin + ci] = f2bf(a.wsrc[r][i]);
    return;
  }
  t -= a.pre[10];
  if (t < 256) { zb[t] = 0.f; return; }
  t -= 256;
  if (t < 384) {
    int co = (int)t; float v = 0.f;
    if (co < 12) v = a.bbox_b[co];
    else if (co < 255) v = a.conf_b[co - 12];
    else if (co < HCOUT) v = a.mask_b[co - 255];
    bias_h[co] = v; return;
  }
  t -= 384;
  if (t < 768) {
    float v = (t < 256) ? a.pb2[t] : (t < 512 ? a.pb1[t - 256] : a.pb0[t - 512]);
    biasP[t] = v; return;
  }
  t -= 768;
  if (t < 768) {
    float v = (t < 256) ? a.lb5[t] : (t < 512 ? a.lb4[t - 256] : a.lb3[t - 512]);
    biasLat[t] = v; return;
  }
  t -= 768;
  if (t < NPTOT) {
    int pi = (int)t;
    const int sizes[5] = {67, 33, 16, 8, 4};
    int idx = pi, H = 4;
#pragma unroll
    for (int L = 0; L < 5; ++L) {
      int cnt = sizes[L] * sizes[L] * 3;
      if (idx < cnt) { H = sizes[L]; break; }
      idx -= cnt;
    }
    int ar = idx % 3; int cell = idx / 3;
    int x = cell % H; int y = cell / H;
    const float ars[3] = {1.0f, 0.5f, 2.0f};
    priors[pi * 4 + 0] = (x + 0.5f) / (float)H;
    priors[pi * 4 + 1] = (y + 0.5f) / (float)H;
    priors[pi * 4 + 2] = 3.0f * ars[ar] / (float)H;
    priors[pi * 4 + 3] = 3.0f / ars[ar] / (float)H;
  }
}

// ---------------------------------------------------------------------------
// table-driven fp32 NCHW -> bf16 NHWC transpose (up to 3 levels per launch)
struct TTab {
  int pre[4];                       // block prefix; pre[nL] = total
  int nx[3];                        // pixel-tile count per level
  int C[3], HW[3];
  unsigned long long dOff[3];       // dest element offsets in R
};
__global__ __launch_bounds__(256) void k_tonhwcN(
    TTab t, const float* __restrict__ s0, const float* __restrict__ s1,
    const float* __restrict__ s2, unsigned short* __restrict__ R) {
  __shared__ float sm[64][65];
  int L = 0, bx = blockIdx.x;
  while (bx >= t.pre[L + 1]) ++L;
  const int tI = bx - t.pre[L];
  const int p0 = (tI % t.nx[L]) * 64, c0 = (tI / t.nx[L]) * 64;
  const int C = t.C[L], HW = t.HW[L], b = blockIdx.z;
  const float* src = (L == 0) ? s0 : (L == 1 ? s1 : s2);
  const int tid = threadIdx.x;
  const float* ib = src + ((size_t)b * C + c0) * HW;
#pragma unroll 4
  for (int r = 0; r < 16; ++r) {
    int ch = r * 4 + (tid >> 6);
    int px = tid & 63;
    sm[ch][px] = (p0 + px < HW) ? ib[(size_t)ch * HW + p0 + px] : 0.f;
  }
  __syncthreads();
#pragma unroll 4
  for (int r = 0; r < 16; ++r) {
    int px = r * 4 + (tid >> 6);
    int ch = tid & 63;
    if (p0 + px < HW)
      R[t.dOff[L] + ((size_t)b * HW + p0 + px) * C + c0 + ch] = f2bf(sm[ch][px]);
  }
}

// ---------------------------------------------------------------------------
// jax-exact bilinear resize add, bf16 NHWC, C=256. thread = 8ch of one out px.
__global__ __launch_bounds__(256) void k_resize_add_nhwc(
    const unsigned short* __restrict__ in, unsigned short* __restrict__ out,
    int Hi, int Wi, int Ho, int Wo) {
  int idx = blockIdx.x * 256 + threadIdx.x;
  int HW = Ho * Wo;
  if (idx >= HW * 32) return;
  int b = blockIdx.z;
  int c0 = (idx & 31) * 8;
  int p = idx >> 5;
  int y = p / Wo, x = p - y * Wo;
  float sy = (y + 0.5f) * (float)Hi / (float)Ho - 0.5f;
  float sx = (x + 0.5f) * (float)Wi / (float)Wo - 0.5f;
  int iy0 = (int)floorf(sy), ix0 = (int)floorf(sx);
  float wy1 = sy - (float)iy0, wy0 = 1.f - wy1;
  float wx1 = sx - (float)ix0, wx0 = 1.f - wx1;
  if (iy0 < 0 || iy0 >= Hi) wy0 = 0.f;
  if (iy0 + 1 < 0 || iy0 + 1 >= Hi) wy1 = 0.f;
  if (ix0 < 0 || ix0 >= Wi) wx0 = 0.f;
  if (ix0 + 1 < 0 || ix0 + 1 >= Wi) wx1 = 0.f;
  float ty_ = wy0 + wy1, tx_ = wx0 + wx1;
  wy0 /= ty_; wy1 /= ty_; wx0 /= tx_; wx1 /= tx_;
  int y0 = min(max(iy0, 0), Hi - 1), y1 = min(max(iy0 + 1, 0), Hi - 1);
  int x0 = min(max(ix0, 0), Wi - 1), x1 = min(max(ix0 + 1, 0), Wi - 1);
  const unsigned short* ib = in + (size_t)b * Hi * Wi * 256;
  u16x8 v00 = *(const u16x8*)&ib[((size_t)y0 * Wi + x0) * 256 + c0];
  u16x8 v01 = *(const u16x8*)&ib[((size_t)y0 * Wi + x1) * 256 + c0];
  u16x8 v10 = *(const u16x8*)&ib[((size_t)y1 * Wi + x0) * 256 + c0];
  u16x8 v11 = *(const u16x8*)&ib[((size_t)y1 * Wi + x1) * 256 + c0];
  unsigned short* ob = out + ((size_t)b * HW + p) * 256 + c0;
  u16x8 cur = *(u16x8*)ob, res;
#pragma unroll
  for (int i = 0; i < 8; ++i) {
    float bl = wy0 * (wx0 * bf2f(v00[i]) + wx1 * bf2f(v01[i])) +
               wy1 * (wx0 * bf2f(v10[i]) + wx1 * bf2f(v11[i]));
    res[i] = f2bf(bf2f(cur[i]) + bl);
  }
  *(u16x8*)ob = res;
}

// ---------------------------------------------------------------------------
__global__ __launch_bounds__(256) void k_down_nhwc(
    const unsigned short* __restrict__ in, unsigned short* __restrict__ out,
    int Hi, int Wi) {
  int Ho = Hi / 2, Wo = Wi / 2, HW = Ho * Wo;
  int idx = blockIdx.x * 256 + threadIdx.x;
  if (idx >= HW * 32) return;
  int b = blockIdx.z;
  int c0 = (idx & 31) * 8;
  int p = idx >> 5;
  int y = p / Wo, x = p - y * Wo;
  *(u16x8*)&out[((size_t)b * HW + p) * 256 + c0] =
      *(const u16x8*)&in[((size_t)b * Hi * Wi + (size_t)(2 * y) * Wi + 2 * x) * 256 + c0];
}

// ---------------------------------------------------------------------------
__global__ __launch_bounds__(256) void priors_kernel(float* __restrict__ pr) {
  int pi = blockIdx.x * 256 + threadIdx.x;
  if (pi >= NPTOT) return;
  const int sizes[5] = {67, 33, 16, 8, 4};
  int idx = pi, H = 4;
#pragma unroll
  for (int L = 0; L < 5; ++L) {
    int cnt = sizes[L] * sizes[L] * 3;
    if (idx < cnt) { H = sizes[L]; break; }
    idx -= cnt;
  }
  int a = idx % 3; int cell = idx / 3;
  int x = cell % H; int y = cell / H;
  const float ars[3] = {1.0f, 0.5f, 2.0f};
  pr[pi * 4 + 0] = (x + 0.5f) / (float)H;
  pr[pi * 4 + 1] = (y + 0.5f) / (float)H;
  pr[pi * 4 + 2] = 3.0f * ars[a] / (float)H;
  pr[pi * 4 + 3] = 3.0f / ars[a] / (float)H;
}

// ---------------------------------------------------------------------------
extern "C" void kernel_launch(void* const* d_in, const int* in_sizes, int n_in,
                              void* d_out, int out_size, void* d_ws, size_t ws_size,
                              hipStream_t stream) {
  const float* c3 = (const float*)d_in[0];
  const float* c4 = (const float*)d_in[1];
  const float* c5 = (const float*)d_in[2];
  const float* lat_w5 = (const float*)d_in[3];  const float* lat_b5 = (const float*)d_in[4];
  const float* lat_w4 = (const float*)d_in[5];  const float* lat_b4 = (const float*)d_in[6];
  const float* lat_w3 = (const float*)d_in[7];  const float* lat_b3 = (const float*)d_in[8];
  const float* pred_w0 = (const float*)d_in[9];  const float* pred_b0 = (const float*)d_in[10];
  const float* pred_w1 = (const float*)d_in[11]; const float* pred_b1 = (const float*)d_in[12];
  const float* pred_w2 = (const float*)d_in[13]; const float* pred_b2 = (const float*)d_in[14];
  const float* up_w = (const float*)d_in[15];  const float* up_b = (const float*)d_in[16];
  const float* bbox_w = (const float*)d_in[17]; const float* bbox_b = (const float*)d_in[18];
  const float* conf_w = (const float*)d_in[19]; const float* conf_b = (const float*)d_in[20];
  const float* mask_w = (const float*)d_in[21]; const float* mask_b = (const float*)d_in[22];

  float* out = (float*)d_out;
  float* priors = out + (size_t)8 * NPTOT * FEAT;

  // workspace layout (bf16 element offsets); peak 48,701,696 elem = 97.40 MB
  unsigned short* B0 = (unsigned short*)d_ws;
  unsigned short* w2_pred0 = B0 + 524288;    // (lat5 at 0)
  unsigned short* w2_up    = B0 + 2686976;
  unsigned short* w2_head  = B0 + 3276800;   // 9*384*256 = 884736 -> 4161536
  unsigned short* x5 = B0 + 4161536;         // 663552   -> 4825088
  unsigned short* x4 = B0 + 4825088;         // 2508800  -> 7333888
  unsigned short* x3 = B0 + 7333888;         // 9750528  -> 17084416
  unsigned short* P  = B0 + 17084416;        // 12111872 -> 29196288 (p3..p7 concat)
  unsigned short* R  = B0 + 29196288;        // 19501056 -> 48697344
  float* bias_h  = (float*)(B0 + 48697344);  // 384 f32  -> 48698112
  float* zb      = (float*)(B0 + 48698112);  // 256 f32  -> 48698624
  float* biasP   = (float*)(B0 + 48698624);  // 768 f32  -> 48700160
  float* biasLat = (float*)(B0 + 48700160);  // 768 f32  -> 48701696
  // P level pixel offsets (px, per level, batch-major inside level)
  const int pxP[5] = {0, 35912, 44624, 46672, 47184};   // p3,p4,p5,p6,p7
  unsigned short* p5 = P + (size_t)pxP[2] * 256;
  unsigned short* p6 = P + (size_t)pxP[3] * 256;
  unsigned short* p7 = P + (size_t)pxP[4] * 256;
  unsigned short* U  = R;                    // R dead after FPN; 12.1M <= 19.5M

  if (ws_size < 48701696ull * 2ull) {        // diagnostic: priors only
    priors_kernel<<<dim3((NPTOT + 255) / 256), dim3(256), 0, stream>>>(priors);
    return;
  }

  // ---- ONE fused prep launch (after zero-padding head weights) ----
  hipMemsetAsync(w2_head, 0, 9ull * HROWS * 256 * 2, stream);
  {
    WPrepArgs a{};
    const float* srcs[10] = {lat_w5, pred_w0, lat_w4, pred_w1, lat_w3, pred_w2,
                             up_w, bbox_w, conf_w, mask_w};
    const unsigned long long dsts[10] = {0, 524288, 1114112, 1376256, 1966080,
                                         2097152, 2686976, 3276800, 3276800, 3276800};
    const int cins[10] = {2048, 256, 1024, 256, 512, 256, 256, 256, 256, 256};
    const int ntaps[10] = {1, 9, 1, 9, 1, 9, 9, 9, 9, 9};
    const int couts[10] = {256, 256, 256, 256, 256, 256, 256, 12, 243, 96};
    const int rss[10] = {256, 256, 256, 256, 256, 256, 256, HROWS, HROWS, HROWS};
    const int ros[10] = {0, 0, 0, 0, 0, 0, 0, 0, 12, 255};
    long long cum = 0;
    for (int i = 0; i < 10; ++i) {
      a.wsrc[i] = srcs[i]; a.wdstOff[i] = dsts[i];
      a.CinA[i] = cins[i]; a.ntapA[i] = ntaps[i]; a.rsA[i] = rss[i]; a.roA[i] = ros[i];
      a.pre[i] = cum;
      cum += (long long)cins[i] * ntaps[i] * couts[i];
    }
    a.pre[10] = cum;                           // = 4,085,504
    a.bbox_b = bbox_b; a.conf_b = conf_b; a.mask_b = mask_b;
    a.pb0 = pred_b0; a.pb1 = pred_b1; a.pb2 = pred_b2;
    a.lb5 = lat_b5; a.lb4 = lat_b4; a.lb3 = lat_b3;
    long long total = cum + 256 + 384 + 768 + 768 + NPTOT;
    k_wprep<<<dim3((unsigned)((total + 255) / 256)), dim3(256), 0, stream>>>(
        a, B0, zb, bias_h, biasP, biasLat, priors);
  }

  // ---- group A: transpose c5+c4 concat into R (15.3M <= 19.5M elems) ----
  {
    TTab t{};
    t.pre[0] = 0; t.pre[1] = 192; t.pre[2] = 512; t.pre[3] = 512;
    t.nx[0] = 6;  t.nx[1] = 20;
    t.C[0] = 2048; t.C[1] = 1024;
    t.HW[0] = 324; t.HW[1] = 1225;
    t.dOff[0] = 0ull; t.dOff[1] = 5308416ull;       // 8*324*2048
    k_tonhwcN<<<dim3(512, 1, 8), dim3(256), 0, stream>>>(t, c5, c4, c3, R);
  }
  // ---- batched lateral conv {lat5->x5, lat4->x4} ----
  {
    LvTab lv{};
    const int Hs[2] = {18, 35};
    const int cins[2] = {2048, 1024};
    const int pxIn[2] = {0, 5184};             // 5,308,416 / 1024
    const int pxOut[2] = {0, 2592};            // x4 rel x5 (px, stride 256)
    const long long wOff[2] = {0, 1114112};
    int acc_ = 0;
    for (int i = 0; i < 2; ++i) {
      lv.pre[i] = acc_;
      acc_ += (Hs[i] * Hs[i] + 127) / 128;
      lv.Hi[i] = Hs[i]; lv.Wi[i] = Hs[i]; lv.Ho[i] = Hs[i]; lv.Wo[i] = Hs[i];
      lv.Cin[i] = cins[i]; lv.pxIn[i] = pxIn[i]; lv.pxOut[i] = pxOut[i];
      lv.pbase[i] = 0; lv.bOff[i] = i * 256; lv.wOff[i] = wOff[i];
    }
    lv.pre[2] = acc_; lv.pre[3] = lv.pre[4] = lv.pre[5] = 2000000000;
    dim3 g(acc_, 2, 8);
    k_conv<1><<<g, dim3(256), 0, stream>>>(R, B0, biasLat, x5, zb, lv,
                                           0, 256, 256, 0, 0);
  }
  // ---- group B: transpose c3 into R (19.5M = R exactly) + lat3->x3 ----
  {
    TTab t{};
    t.pre[0] = 0; t.pre[1] = 600; t.pre[2] = 600; t.pre[3] = 600;
    t.nx[0] = 75; t.C[0] = 512; t.HW[0] = 4761; t.dOff[0] = 0ull;
    k_tonhwcN<<<dim3(600, 1, 8), dim3(256), 0, stream>>>(t, c3, c4, c5, R);
  }
  {
    LvTab lv{};
    lv.pre[0] = 0; lv.pre[1] = 38;             // ceil(4761/128)
    lv.pre[2] = lv.pre[3] = lv.pre[4] = lv.pre[5] = 2000000000;
    lv.Hi[0] = 69; lv.Wi[0] = 69; lv.Ho[0] = 69; lv.Wo[0] = 69;
    lv.Cin[0] = 512; lv.pxIn[0] = 0; lv.pxOut[0] = 12392;   // x3 rel x5
    lv.pbase[0] = 0; lv.bOff[0] = 512; lv.wOff[0] = 1966080;
    dim3 g(38, 2, 8);
    k_conv<1><<<g, dim3(256), 0, stream>>>(R, B0, biasLat, x5, zb, lv,
                                           0, 256, 256, 0, 0);
  }

  // ---- resize chain (serial dependency) ----
  k_resize_add_nhwc<<<dim3((1225 * 32 + 255) / 256, 1, 8), dim3(256), 0, stream>>>(x5, x4, 18, 18, 35, 35);
  k_resize_add_nhwc<<<dim3((4761 * 32 + 255) / 256, 1, 8), dim3(256), 0, stream>>>(x4, x3, 35, 35, 69, 69);

  // ---- pred convs: ONE batched launch (pred2->p3, pred1->p4, pred0->p5) ----
  {
    LvTab lv{};
    const int HiL[3] = {69, 35, 18}, HoL[3] = {67, 33, 16};
    const long long wOffL[3] = {1572864, 851968, 0};   // pred2/1/0 rel w2_pred0
    const int pxInL[3]  = {12392, 2592, 0};            // x3/x4/x5 rel x5 (px)
    const int pxOutL[3] = {0, 35912, 44624};           // p3/p4/p5 in P
    const int bOffL[3]  = {0, 256, 512};               // biasP packing
    int acc_ = 0;
    for (int i = 0; i < 3; ++i) {
      lv.pre[i] = acc_;
      acc_ += (HoL[i] * HoL[i] + 127) / 128;
      lv.pxIn[i] = pxInL[i]; lv.pxOut[i] = pxOutL[i];
      lv.Hi[i] = HiL[i]; lv.Wi[i] = HiL[i]; lv.Ho[i] = HoL[i]; lv.Wo[i] = HoL[i];
      lv.pbase[i] = 0; lv.Cin[i] = 256; lv.bOff[i] = bOffL[i]; lv.wOff[i] = wOffL[i];
    }
    lv.pre[3] = acc_; lv.pre[4] = lv.pre[5] = 2000000000;
    dim3 g(acc_, 2, 8);
    k_conv<9><<<g, dim3(256), 0, stream>>>(x5, w2_pred0, biasP, P, zb, lv,
                                           0, 256, 256, 1, 0);
  }
  k_down_nhwc<<<dim3((64 * 32 + 255) / 256, 1, 8), dim3(256), 0, stream>>>(p5, p6, 16, 16);
  k_down_nhwc<<<dim3((16 * 32 + 255) / 256, 1, 8), dim3(256), 0, stream>>>(p6, p7, 8, 8);

  // ---- heads: ONE batched up-conv + ONE batched fused head conv ----
  const int Hl[5] = {67, 33, 16, 8, 4};
  const int pbl[5] = {0, 13467, 16734, 17502, 17694};
  auto conv5 = [&](const unsigned short* in_, const unsigned short* w2_, const float* b_,
                   void* out_, int Cout, int CoutRows, int relu, int outMode) {
    LvTab lv{};
    int acc_ = 0;
    for (int i = 0; i < 5; ++i) {
      lv.pre[i] = acc_;
      acc_ += (Hl[i] * Hl[i] + 127) / 128;
      lv.pxIn[i] = pxP[i]; lv.pxOut[i] = pxP[i];
      lv.Hi[i] = Hl[i]; lv.Wi[i] = Hl[i]; lv.Ho[i] = Hl[i]; lv.Wo[i] = Hl[i];
      lv.pbase[i] = pbl[i]; lv.Cin[i] = 256; lv.bOff[i] = 0; lv.wOff[i] = 0;
    }
    lv.pre[5] = acc_;
    dim3 g(acc_, (Cout + 127) / 128, 8);
    k_conv<9><<<g, dim3(256), 0, stream>>>(in_, w2_, b_, out_, zb, lv,
                                           1, Cout, CoutRows, relu, outMode);
  };
  conv5(P, w2_up, up_b, U, 256, 256, 1, 0);
  conv5(U, w2_head, bias_h, out, HCOUT, HROWS, 0, 1);
}